// Round 4
// baseline (706.480 us; speedup 1.0000x reference)
//
#include <hip/hip_runtime.h>

typedef __bf16 bf16_t;
typedef __bf16 bf16x8 __attribute__((ext_vector_type(8)));
typedef float f32x4 __attribute__((ext_vector_type(4)));

#define D_MODEL 1024
#define NH      16
#define DH      64
#define SEQ     2048
#define BATCH   4
#define MROWS   (BATCH * SEQ)   // 8192

// ---------------------------------------------------------------------------
// Transpose+convert 1024x1024 fp32 weights -> bf16: out[n][k] = (bf16)in[k][n]
// grid (32,32,4), block (32,8)
// ---------------------------------------------------------------------------
__global__ void transpose_w(const float* __restrict__ W0, const float* __restrict__ W1,
                            const float* __restrict__ W2, const float* __restrict__ W3,
                            bf16_t* __restrict__ out) {
    __shared__ bf16_t tile[32][33];
    const int z = blockIdx.z;
    const float* src = (z == 0) ? W0 : (z == 1) ? W1 : (z == 2) ? W2 : W3;
    bf16_t* dst = out + (size_t)z * (D_MODEL * D_MODEL);
    const int bx = blockIdx.x * 32, by = blockIdx.y * 32;
    const int tx = threadIdx.x, ty = threadIdx.y;
#pragma unroll
    for (int i = 0; i < 4; ++i)
        tile[ty + i * 8][tx] = (bf16_t)src[(size_t)(by + ty + i * 8) * D_MODEL + bx + tx];
    __syncthreads();
#pragma unroll
    for (int i = 0; i < 4; ++i)
        dst[(size_t)(bx + ty + i * 8) * D_MODEL + by + tx] = tile[tx][ty + i * 8];
}

// ---------------------------------------------------------------------------
// Projection GEMM: C[m][n] = (sum_k A[m][k]*Wt[n][k] + bias[n]) * scale
// A: (M x 1024) row-major (fp32 or bf16 per template), Wt: bf16 (= W^T)
// bias: fp32. C: bf16 or fp32 per template.
// grid (N/128=8, M/128), block 256 (4 waves, 2x2 of 64x64)
// ---------------------------------------------------------------------------
#define LDS_STRIDE 40
template<bool A_IS_F32, bool OUT_F32>
__global__ __launch_bounds__(256) void proj_gemm(const void* __restrict__ A_,
                                                 const bf16_t* __restrict__ Wt,
                                                 const float* __restrict__ bias,
                                                 void* __restrict__ C_,
                                                 float scale) {
    __shared__ __align__(16) bf16_t As[128 * LDS_STRIDE];
    __shared__ __align__(16) bf16_t Bs[128 * LDS_STRIDE];
    const int tid  = threadIdx.x;
    const int lane = tid & 63;
    const int w    = tid >> 6;           // wave 0..3
    const int wrow = (w >> 1) * 64;
    const int wcol = (w & 1) * 64;
    const int m0 = blockIdx.y * 128;
    const int n0 = blockIdx.x * 128;
    const int l15  = lane & 15;
    const int quad = lane >> 4;
    const int srow = tid >> 2;           // 0..63
    const int sq   = (tid & 3) * 8;      // 0,8,16,24

    f32x4 acc[4][4];
#pragma unroll
    for (int i = 0; i < 4; ++i)
#pragma unroll
        for (int j = 0; j < 4; ++j)
#pragma unroll
            for (int r = 0; r < 4; ++r) acc[i][j][r] = 0.0f;

    for (int kt = 0; kt < 32; ++kt) {
        const int k0 = kt * 32;
#pragma unroll
        for (int rd = 0; rd < 2; ++rd) {
            const int row = rd * 64 + srow;
            if (A_IS_F32) {
                const float* A = (const float*)A_;
                const float4 x = *(const float4*)(A + (size_t)(m0 + row) * D_MODEL + k0 + sq);
                const float4 y = *(const float4*)(A + (size_t)(m0 + row) * D_MODEL + k0 + sq + 4);
                bf16x8 t;
                t[0] = (bf16_t)x.x; t[1] = (bf16_t)x.y; t[2] = (bf16_t)x.z; t[3] = (bf16_t)x.w;
                t[4] = (bf16_t)y.x; t[5] = (bf16_t)y.y; t[6] = (bf16_t)y.z; t[7] = (bf16_t)y.w;
                *(bf16x8*)&As[row * LDS_STRIDE + sq] = t;
            } else {
                const bf16_t* A = (const bf16_t*)A_;
                *(bf16x8*)&As[row * LDS_STRIDE + sq] =
                    *(const bf16x8*)(A + (size_t)(m0 + row) * D_MODEL + k0 + sq);
            }
            *(bf16x8*)&Bs[row * LDS_STRIDE + sq] =
                *(const bf16x8*)(Wt + (size_t)(n0 + row) * D_MODEL + k0 + sq);
        }
        __syncthreads();
        bf16x8 af[4], bf[4];
#pragma unroll
        for (int mi = 0; mi < 4; ++mi)
            af[mi] = *(const bf16x8*)&As[(wrow + mi * 16 + l15) * LDS_STRIDE + quad * 8];
#pragma unroll
        for (int ni = 0; ni < 4; ++ni)
            bf[ni] = *(const bf16x8*)&Bs[(wcol + ni * 16 + l15) * LDS_STRIDE + quad * 8];
#pragma unroll
        for (int mi = 0; mi < 4; ++mi)
#pragma unroll
            for (int ni = 0; ni < 4; ++ni)
                acc[mi][ni] = __builtin_amdgcn_mfma_f32_16x16x32_bf16(af[mi], bf[ni], acc[mi][ni], 0, 0, 0);
        __syncthreads();
    }

#pragma unroll
    for (int ni = 0; ni < 4; ++ni) {
        const int col = n0 + wcol + ni * 16 + l15;
        const float bc = bias[col];
#pragma unroll
        for (int mi = 0; mi < 4; ++mi) {
#pragma unroll
            for (int r = 0; r < 4; ++r) {
                const int row = m0 + wrow + mi * 16 + quad * 4 + r;
                const float v = (acc[mi][ni][r] + bc) * scale;
                if (OUT_F32) ((float*)C_)[(size_t)row * D_MODEL + col] = v;
                else         ((bf16_t*)C_)[(size_t)row * D_MODEL + col] = (bf16_t)v;
            }
        }
    }
}

// ---------------------------------------------------------------------------
// Flash attention: grid (32 q-tiles, 64 bh), block 256 (4 waves x 16 q-rows)
// ctx[b*2048+q][h*64+d] = softmax(QK^T) V   (all bf16 in/out, fp32 accumulate)
// ---------------------------------------------------------------------------
__global__ __launch_bounds__(256) void flash_attn(const bf16_t* __restrict__ Qu,
                                                  const bf16_t* __restrict__ Ku,
                                                  const bf16_t* __restrict__ Vu,
                                                  bf16_t* __restrict__ ctx) {
    const int qt = blockIdx.x;           // 0..31
    const int bh = blockIdx.y;           // 0..63
    const int b = bh >> 4, h = bh & 15;
    const int tid  = threadIdx.x;
    const int lane = tid & 63;
    const int w    = tid >> 6;
    const int l15  = lane & 15;
    const int quad = lane >> 4;

    __shared__ __align__(16) bf16_t Vt[64][72];       // [d][key]
    __shared__ __align__(16) bf16_t Ps[4][16][72];    // [wave][q][key]

    const size_t base_b = (size_t)b * SEQ * D_MODEL + (size_t)h * DH;
    const int qrow0 = qt * 64 + w * 16;

    bf16x8 qf[2];
#pragma unroll
    for (int ks = 0; ks < 2; ++ks)
        qf[ks] = *(const bf16x8*)(Qu + base_b + (size_t)(qrow0 + l15) * D_MODEL + ks * 32 + quad * 8);

    float m_r[4], l_r[4];
    f32x4 cacc[4];
#pragma unroll
    for (int r = 0; r < 4; ++r) { m_r[r] = -__builtin_inff(); l_r[r] = 0.0f; }
#pragma unroll
    for (int ds = 0; ds < 4; ++ds)
#pragma unroll
        for (int r = 0; r < 4; ++r) cacc[ds][r] = 0.0f;

    const int vkey = tid >> 2;           // 0..63
    const int vd8  = (tid & 3) * 8;      // 0,8,16,24

    for (int kt = 0; kt < 32; ++kt) {
        const int kb = kt * 64;
        // stage V transposed into LDS
#pragma unroll
        for (int half = 0; half < 2; ++half) {
            const int d = half * 32 + vd8;
            bf16x8 v = *(const bf16x8*)(Vu + base_b + (size_t)(kb + vkey) * D_MODEL + d);
#pragma unroll
            for (int i = 0; i < 8; ++i) Vt[d + i][vkey] = v[i];
        }
        // QK^T
        f32x4 s[4];
#pragma unroll
        for (int ki = 0; ki < 4; ++ki)
#pragma unroll
            for (int r = 0; r < 4; ++r) s[ki][r] = 0.0f;
#pragma unroll
        for (int ks = 0; ks < 2; ++ks)
#pragma unroll
            for (int ki = 0; ki < 4; ++ki) {
                bf16x8 kf = *(const bf16x8*)(Ku + base_b + (size_t)(kb + ki * 16 + l15) * D_MODEL + ks * 32 + quad * 8);
                s[ki] = __builtin_amdgcn_mfma_f32_16x16x32_bf16(qf[ks], kf, s[ki], 0, 0, 0);
            }
        // online softmax (rows = quad*4+r, cols across the quad's 16 lanes)
        float mn[4], al[4];
#pragma unroll
        for (int r = 0; r < 4; ++r) {
            float v = fmaxf(fmaxf(s[0][r], s[1][r]), fmaxf(s[2][r], s[3][r]));
#pragma unroll
            for (int off = 1; off < 16; off <<= 1) v = fmaxf(v, __shfl_xor(v, off, 16));
            mn[r] = fmaxf(m_r[r], v);
            al[r] = __expf(m_r[r] - mn[r]);
            m_r[r] = mn[r];
        }
        float p[4][4];
#pragma unroll
        for (int ki = 0; ki < 4; ++ki)
#pragma unroll
            for (int r = 0; r < 4; ++r) p[ki][r] = __expf(s[ki][r] - mn[r]);
#pragma unroll
        for (int r = 0; r < 4; ++r) {
            float t = p[0][r] + p[1][r] + p[2][r] + p[3][r];
#pragma unroll
            for (int off = 1; off < 16; off <<= 1) t += __shfl_xor(t, off, 16);
            l_r[r] = l_r[r] * al[r] + t;
        }
#pragma unroll
        for (int ds = 0; ds < 4; ++ds)
#pragma unroll
            for (int r = 0; r < 4; ++r) cacc[ds][r] *= al[r];
        // P -> LDS (bf16)
#pragma unroll
        for (int ki = 0; ki < 4; ++ki)
#pragma unroll
            for (int r = 0; r < 4; ++r)
                Ps[w][quad * 4 + r][ki * 16 + l15] = (bf16_t)p[ki][r];
        __syncthreads();
        // PV
#pragma unroll
        for (int ks = 0; ks < 2; ++ks) {
            bf16x8 af = *(const bf16x8*)&Ps[w][l15][ks * 32 + quad * 8];
#pragma unroll
            for (int ds = 0; ds < 4; ++ds) {
                bf16x8 vf = *(const bf16x8*)&Vt[ds * 16 + l15][ks * 32 + quad * 8];
                cacc[ds] = __builtin_amdgcn_mfma_f32_16x16x32_bf16(af, vf, cacc[ds], 0, 0, 0);
            }
        }
        __syncthreads();
    }
    // epilogue
#pragma unroll
    for (int r = 0; r < 4; ++r) {
        const float rl = 1.0f / l_r[r];
        const int q = qrow0 + quad * 4 + r;
#pragma unroll
        for (int ds = 0; ds < 4; ++ds)
            ctx[(size_t)(b * SEQ + q) * D_MODEL + h * DH + ds * 16 + l15] = (bf16_t)(cacc[ds][r] * rl);
    }
}

// ---------------------------------------------------------------------------
// Head-0 attention matrix, recomputed: grid (32 q-tiles, 4 b), block 256.
// Pass A: running max/sum over keys. Pass B: write exp(s-m)/l as FP32.
// ---------------------------------------------------------------------------
__global__ __launch_bounds__(256) void attn_h0(const bf16_t* __restrict__ Qu,
                                               const bf16_t* __restrict__ Ku,
                                               float* __restrict__ out) {
    const int qt = blockIdx.x;           // 0..31
    const int b  = blockIdx.y;           // 0..3
    const int tid  = threadIdx.x;
    const int lane = tid & 63;
    const int w    = tid >> 6;
    const int l15  = lane & 15;
    const int quad = lane >> 4;

    const size_t base_b = (size_t)b * SEQ * D_MODEL;   // head 0
    const int qrow0 = qt * 64 + w * 16;

    bf16x8 qf[2];
#pragma unroll
    for (int ks = 0; ks < 2; ++ks)
        qf[ks] = *(const bf16x8*)(Qu + base_b + (size_t)(qrow0 + l15) * D_MODEL + ks * 32 + quad * 8);

    float m_r[4], l_r[4];
#pragma unroll
    for (int r = 0; r < 4; ++r) { m_r[r] = -__builtin_inff(); l_r[r] = 0.0f; }

    // Pass A: running max & sum
    for (int kt = 0; kt < 32; ++kt) {
        const int kb = kt * 64;
        f32x4 s[4];
#pragma unroll
        for (int ki = 0; ki < 4; ++ki)
#pragma unroll
            for (int r = 0; r < 4; ++r) s[ki][r] = 0.0f;
#pragma unroll
        for (int ks = 0; ks < 2; ++ks)
#pragma unroll
            for (int ki = 0; ki < 4; ++ki) {
                bf16x8 kf = *(const bf16x8*)(Ku + base_b + (size_t)(kb + ki * 16 + l15) * D_MODEL + ks * 32 + quad * 8);
                s[ki] = __builtin_amdgcn_mfma_f32_16x16x32_bf16(qf[ks], kf, s[ki], 0, 0, 0);
            }
#pragma unroll
        for (int r = 0; r < 4; ++r) {
            float v = fmaxf(fmaxf(s[0][r], s[1][r]), fmaxf(s[2][r], s[3][r]));
#pragma unroll
            for (int off = 1; off < 16; off <<= 1) v = fmaxf(v, __shfl_xor(v, off, 16));
            const float mn = fmaxf(m_r[r], v);
            const float al = __expf(m_r[r] - mn);
            m_r[r] = mn;
            float t = __expf(s[0][r] - mn) + __expf(s[1][r] - mn)
                    + __expf(s[2][r] - mn) + __expf(s[3][r] - mn);
#pragma unroll
            for (int off = 1; off < 16; off <<= 1) t += __shfl_xor(t, off, 16);
            l_r[r] = l_r[r] * al + t;
        }
    }
    float rl[4];
#pragma unroll
    for (int r = 0; r < 4; ++r) rl[r] = 1.0f / l_r[r];

    // Pass B: recompute and write normalized probabilities (fp32)
    for (int kt = 0; kt < 32; ++kt) {
        const int kb = kt * 64;
        f32x4 s[4];
#pragma unroll
        for (int ki = 0; ki < 4; ++ki)
#pragma unroll
            for (int r = 0; r < 4; ++r) s[ki][r] = 0.0f;
#pragma unroll
        for (int ks = 0; ks < 2; ++ks)
#pragma unroll
            for (int ki = 0; ki < 4; ++ki) {
                bf16x8 kf = *(const bf16x8*)(Ku + base_b + (size_t)(kb + ki * 16 + l15) * D_MODEL + ks * 32 + quad * 8);
                s[ki] = __builtin_amdgcn_mfma_f32_16x16x32_bf16(qf[ks], kf, s[ki], 0, 0, 0);
            }
#pragma unroll
        for (int ki = 0; ki < 4; ++ki)
#pragma unroll
            for (int r = 0; r < 4; ++r) {
                const int q = qrow0 + quad * 4 + r;
                out[(size_t)(b * SEQ + q) * SEQ + kb + ki * 16 + l15] =
                    __expf(s[ki][r] - m_r[r]) * rl[r];
            }
    }
}

// ---------------------------------------------------------------------------
extern "C" void kernel_launch(void* const* d_in, const int* in_sizes, int n_in,
                              void* d_out, int out_size, void* d_ws, size_t ws_size,
                              hipStream_t stream) {
    // All inputs/outputs are FP32 (per reference). Internally bf16 MFMA.
    const float* key   = (const float*)d_in[0];
    const float* value = (const float*)d_in[1];
    const float* query = (const float*)d_in[2];
    const float* Wk = (const float*)d_in[3];
    const float* bk = (const float*)d_in[4];
    const float* Wv = (const float*)d_in[5];
    const float* bv = (const float*)d_in[6];
    const float* Wq = (const float*)d_in[7];
    const float* bq = (const float*)d_in[8];
    const float* Wo = (const float*)d_in[9];
    const float* bo = (const float*)d_in[10];

    float* out_proj = (float*)d_out;                            // 8388608 fp32 (32 MiB)
    float* out_attn = (float*)d_out + (size_t)MROWS * D_MODEL;  // 16777216 fp32 (64 MiB)

    // ws layout (40 MiB): Wt(8) | Kup(16) | Qup(16)   [all bf16]
    char* ws = (char*)d_ws;
    bf16_t* Wt  = (bf16_t*)ws;
    bf16_t* Kup = (bf16_t*)(ws + (size_t) 8 * 1024 * 1024);
    bf16_t* Qup = (bf16_t*)(ws + (size_t)24 * 1024 * 1024);
    // Vup(16 MiB) and ctx(16 MiB) live inside the 64 MiB out_attn region;
    // both are dead before attn_h0 overwrites that region at the very end.
    bf16_t* Vup = (bf16_t*)out_attn;
    bf16_t* ctx = Vup + (size_t)MROWS * D_MODEL;

    const bf16_t* Wt_k = Wt;
    const bf16_t* Wt_v = Wt + 1 * D_MODEL * D_MODEL;
    const bf16_t* Wt_q = Wt + 2 * D_MODEL * D_MODEL;
    const bf16_t* Wt_o = Wt + 3 * D_MODEL * D_MODEL;

    transpose_w<<<dim3(32, 32, 4), dim3(32, 8), 0, stream>>>(Wk, Wv, Wq, Wo, Wt);

    proj_gemm<true,  false><<<dim3(8, 64), 256, 0, stream>>>(key,   Wt_k, bk, Kup, 1.0f);
    proj_gemm<true,  false><<<dim3(8, 64), 256, 0, stream>>>(value, Wt_v, bv, Vup, 1.0f);
    proj_gemm<true,  false><<<dim3(8, 64), 256, 0, stream>>>(query, Wt_q, bq, Qup, 0.125f); // 1/sqrt(64)

    flash_attn<<<dim3(32, 64), 256, 0, stream>>>(Qup, Kup, Vup, ctx);

    proj_gemm<false, true ><<<dim3(8, 64), 256, 0, stream>>>(ctx, Wt_o, bo, out_proj, 1.0f);

    attn_h0<<<dim3(32, 4), 256, 0, stream>>>(Qup, Kup, out_attn);
}